// Round 3
// baseline (323.676 us; speedup 1.0000x reference)
//
#include <hip/hip_runtime.h>
#include <hip/hip_bf16.h>

#define B_   2
#define S_   2048
#define D_   2048
#define H_   16
#define KV_  4
#define KQD_ 96
#define VD_  128
#define NQK_ 1920            // H*KQD + KV*KQD = 1536 + 384
#define M_   4096            // B*S

typedef __attribute__((ext_vector_type(8))) short bf16x8;
typedef __attribute__((ext_vector_type(4))) short bf16x4;
typedef __attribute__((ext_vector_type(4))) float f32x4;

__device__ __forceinline__ short f2bf(float f) {
    union { float f; unsigned u; } v; v.f = f;
    unsigned r = (v.u + 0x7fffu + ((v.u >> 16) & 1u)) >> 16;
    return (short)r;
}
__device__ __forceinline__ float bf2f(short s) {
    union { unsigned u; float f; } v; v.u = ((unsigned)(unsigned short)s) << 16;
    return v.f;
}

__device__ __forceinline__ void glds16(const void* g, void* l) {
    __builtin_amdgcn_global_load_lds(
        (__attribute__((address_space(1))) void*)(g),
        (__attribute__((address_space(3))) void*)(l), 16, 0, 0);
}

// DPP-based 16-lane sum (epilogue only)
template <int CTRL>
__device__ __forceinline__ float dppf(float x) {
    return __int_as_float(__builtin_amdgcn_update_dpp(
        0, __float_as_int(x), CTRL, 0xF, 0xF, true));
}
__device__ __forceinline__ float rsum16(float x) {
    x += dppf<0xB1>(x);     // quad_perm xor1
    x += dppf<0x4E>(x);     // quad_perm xor2
    x += dppf<0x124>(x);    // row_ror:4
    x += dppf<0x128>(x);    // row_ror:8
    return x;
}

// ---------------------------------------------------------------------------
// fp32 -> bf16 for all five inputs in one launch; dests contiguous in ws.
// ---------------------------------------------------------------------------
__global__ __launch_bounds__(256) void cvt_all(
    const float* __restrict__ hs, const float* __restrict__ wq,
    const float* __restrict__ wk, const float* __restrict__ wv,
    const float* __restrict__ wo, short* __restrict__ dst)
{
    int i = blockIdx.x * 256 + threadIdx.x;
    if (i >= 4390912) return;
    const float* s; int off;
    if      (i < 2097152) { s = hs; off = i; }
    else if (i < 2883584) { s = wq; off = i - 2097152; }
    else if (i < 3080192) { s = wk; off = i - 2883584; }
    else if (i < 3342336) { s = wv; off = i - 3080192; }
    else                  { s = wo; off = i - 3342336; }
    float4 v = ((const float4*)s)[off];
    bf16x4 o;
    o.x = f2bf(v.x); o.y = f2bf(v.y); o.z = f2bf(v.z); o.w = f2bf(v.w);
    ((bf16x4*)dst)[i] = o;
}

// ---------------------------------------------------------------------------
// GEMM: C[M x N] = A[M x K] * W[N x K]^T   (bf16 in, fp32 acc)
// Double-buffered LDS K-loop, ONE barrier per iter:
// glds(k+1) issued after frag reads of tile k, in flight through the MFMAs.
// OUT==2: fp32 row-major.  OUT==3: fused QKV (cols<NQK_ row-major into Cv,
// cols>=NQK_ transposed V^T into Cv2).
// ---------------------------------------------------------------------------
template <int OUT>
__global__ __launch_bounds__(256) void gemm_bt(
    const short* __restrict__ A, const short* __restrict__ W,
    void* __restrict__ Cv, void* __restrict__ Cv2, int M, int N, int K)
{
    __shared__ short As[2][128 * 32];   // 16 KB
    __shared__ short Ws[2][128 * 32];   // 16 KB

    const int tid  = threadIdx.x;
    const int wv   = tid >> 6;
    const int lane = tid & 63;
    const int wm   = wv >> 1, wn = wv & 1;
    const int m0   = blockIdx.x * 128;
    const int n0   = blockIdx.y * 128;
    const int l16  = lane & 15;
    const int qd   = lane >> 4;

    auto stage = [&](int k0, int buf) {
#pragma unroll
        for (int r = 0; r < 2; ++r) {
            int flat = r * 256 + tid;
            int row = flat >> 2, ch = flat & 3;
            const short* ga = A + (long)(m0 + row) * K + k0 + ch * 8;
            const short* gw = W + (long)(n0 + row) * K + k0 + ch * 8;
            int base = (r * 256 + wv * 64) * 8;
            glds16(ga, As[buf] + base);
            glds16(gw, Ws[buf] + base);
        }
    };

    stage(0, 0);   // prologue

    f32x4 acc[4][4] = {};

    for (int k0 = 0; k0 < K; k0 += 32) {
        const int buf = (k0 >> 5) & 1;
        __syncthreads();   // vmcnt(0): glds(k0) landed (issued 1 iter ago)

        bf16x8 af[4], wf[4];
#pragma unroll
        for (int i = 0; i < 4; ++i) {
            af[i] = *(const bf16x8*)(As[buf] + (wm * 64 + i * 16 + l16) * 32 + qd * 8);
            wf[i] = *(const bf16x8*)(Ws[buf] + (wn * 64 + i * 16 + l16) * 32 + qd * 8);
        }
        if (k0 + 32 < K) stage(k0 + 32, buf ^ 1);   // in flight through MFMAs

#pragma unroll
        for (int i = 0; i < 4; ++i)
#pragma unroll
            for (int j = 0; j < 4; ++j)
                acc[i][j] = __builtin_amdgcn_mfma_f32_16x16x32_bf16(
                    af[i], wf[j], acc[i][j], 0, 0, 0);
    }

    if (OUT == 2) {
        float* C = (float*)Cv;
#pragma unroll
        for (int i = 0; i < 4; ++i) {
            int row0 = m0 + wm * 64 + i * 16 + qd * 4;
#pragma unroll
            for (int j = 0; j < 4; ++j) {
                int col = n0 + wn * 64 + j * 16 + l16;
#pragma unroll
                for (int r = 0; r < 4; ++r)
                    C[(long)(row0 + r) * N + col] = acc[i][j][r];
            }
        }
    } else {  // OUT == 3
        if (n0 < NQK_) {
            short* C = (short*)Cv;
#pragma unroll
            for (int i = 0; i < 4; ++i) {
                int row0 = m0 + wm * 64 + i * 16 + qd * 4;
#pragma unroll
                for (int j = 0; j < 4; ++j) {
                    int col = n0 + wn * 64 + j * 16 + l16;
#pragma unroll
                    for (int r = 0; r < 4; ++r)
                        C[(long)(row0 + r) * NQK_ + col] = f2bf(acc[i][j][r]);
                }
            }
        } else {
            short* C = (short*)Cv2;
#pragma unroll
            for (int i = 0; i < 4; ++i) {
                int row0 = m0 + wm * 64 + i * 16 + qd * 4;
#pragma unroll
                for (int j = 0; j < 4; ++j) {
                    int vcol = n0 - NQK_ + wn * 64 + j * 16 + l16;
                    bf16x4 pk;
                    pk.x = f2bf(acc[i][j][0]); pk.y = f2bf(acc[i][j][1]);
                    pk.z = f2bf(acc[i][j][2]); pk.w = f2bf(acc[i][j][3]);
                    *(bf16x4*)(C + (long)vcol * M_ + row0) = pk;  // V^T
                }
            }
        }
    }
}

// ---------------------------------------------------------------------------
// RMSNorm + RoPE, in place on fused qk buffer (row stride NQK_).
// Q additionally pre-scaled by (1/sqrt(96))*log2(e) -> exp2-domain scores.
// ---------------------------------------------------------------------------
__global__ __launch_bounds__(256) void rms_rope(
    short* __restrict__ qk, const float* __restrict__ qw,
    const float* __restrict__ kw, const int* __restrict__ pos_ids)
{
    int wid  = (int)((blockIdx.x * 256 + threadIdx.x) >> 6);
    int lane = threadIdx.x & 63;

    short* v; const float* w; int row; float qs;
    if (wid < 65536) {                       // q: 4096 rows x 16 heads
        row = wid >> 4;
        v = qk + (long)row * NQK_ + (wid & 15) * 96;
        w = qw;
        qs = 0.14724444f;                    // (1/sqrt(96)) * log2(e)
    } else {                                 // k: 4096 rows x 4 heads
        int t = wid - 65536;
        row = t >> 2;
        v = qk + (long)row * NQK_ + 1536 + (t & 3) * 96;
        w = kw;
        qs = 1.0f;
    }

    float x0 = 0.f, x1 = 0.f;
    if (lane < 48) { x0 = bf2f(v[lane]); x1 = bf2f(v[lane + 48]); }
    float ss = x0 * x0 + x1 * x1;
#pragma unroll
    for (int off = 1; off < 64; off <<= 1) ss += __shfl_xor(ss, off, 64);
    float rr = rsqrtf(ss * (1.0f / 96.0f) + 1e-6f);

    if (lane < 48) {
        int pos = pos_ids[row];
        float y0 = (x0 * rr) * w[lane] * qs;
        float y1 = (x1 * rr) * w[lane + 48] * qs;
        float inv = exp2f(-(float)lane * (13.287712379549449f / 48.0f));
        float fr  = (float)pos * inv;
        float c, s;
        sincosf(fr, &s, &c);
        v[lane]      = f2bf(y0 * c - y1 * s);
        v[lane + 48] = f2bf(y1 * c + y0 * s);
    }
}

// ---------------------------------------------------------------------------
// Flash attention (causal, GQA 4:1). 512-thread blocks, 8 waves =
// 4 q-subtiles (32 rows, wq) x 2 kv-halves (32 cols, we). R2 post-mortem:
// attn is LATENCY-exposed (LDS-pipe floor ~22 us, measured 80, occupancy
// 8 waves/CU). kv-split doubles waves/CU to 16 at IDENTICAL LDS reads per
// unit work (each wave: 18 MFMA, 16 b128 reads, 16 exp2 per tile). Costs a
// once-per-block O/l pair-reduction through LDS (11 barriers, negligible).
// Staging via global_load_lds, double-buffered, one barrier per tile:
//   K: stride 104 shorts = 13 granules, 13 coprime 16 -> b128 frag reads
//      conflict-free (stride 96's 12 granules was a 4-way conflict).
//      Pad granule (ch==12) staged from a dummy source (glds dest linear).
//   V: stride 64, source pre-swizzled granule g = (flat&7) ^ (row&7);
//      read applies same XOR (proven R2).
// Ps: per-wave [32][40] (5 granules, coprime 16 -> reads <=2-way free);
//      col ^= 16 when row&8 puts write octets disjoint -> conflict-free.
// Epilogue: we==1 waves push o (4 phases x 4KB/pair) + rs through Ps space;
// we==0 adds, rsum16, writes out.
// launch_bounds(512,3): >=3 waves/SIMD guaranteed (cap 170 VGPR, no forced
// spill -- R1 lesson). LDS = 26+32+20 = 78 KB -> 2 blocks/CU.
// exp2-domain STATIC-MAX softmax: |q|=|k|=sqrt(96), RoPE norm-preserving,
// score*log2e <= 14.14 < 14.5; p = exp2(s - 14.5), no running max.
// qk: fused (M x NQK_)  vt: (KV*VD x M)  out: (B,S,H*128) bf16
// ---------------------------------------------------------------------------
__global__ __launch_bounds__(512, 3) void attn(
    const short* __restrict__ qk, const short* __restrict__ vt,
    short* __restrict__ out)
{
    __shared__ short Ks[2][64 * 104];    // 26 KB
    __shared__ short Vs[2][128 * 64];    // 32 KB
    __shared__ short Ps[8][32 * 40];     // 20 KB   -> 78 KB total

    const int tid  = threadIdx.x;
    const int lane = tid & 63;
    const int wv   = tid >> 6;           // 0..7
    const int wq   = wv & 3;             // q-subtile (32 rows)
    const int we   = wv >> 2;            // kv half (32 cols)
    const int bh   = blockIdx.x;         // 0..31
    const int qi   = blockIdx.y;         // 0..15
    const int b    = bh >> 4, h = bh & 15;
    const int kvh  = h >> 2;
    const int l16  = lane & 15;
    const int qd   = lane >> 4;
    const long bS  = (long)b * S_;

    const int qt = (qi < 8) ? (15 - qi) : (qi - 8);   // balance map
    const int q0 = qt * 128;
    const int nt = 2 * qt + 2;                         // kv tiles (64 each)

    const short* kbase = qk + bS * NQK_ + 1536 + kvh * 96;
    const short* vbase = vt + (long)kvh * 128 * (B_ * S_) + bS;

    auto stage = [&](int k0, int buf) {
        // K: 64 rows x 13 granules (12 data + 1 pad) = 832 = 512+256+64
        auto kst = [&](int flat, int gbase) {
            int row = flat / 13, ch = flat % 13;
            const short* src = (ch < 12)
                ? (kbase + (long)(k0 + row) * NQK_ + ch * 8) : kbase;
            glds16(src, Ks[buf] + gbase * 8);
        };
        kst(tid, wv * 64);
        if (tid < 256) kst(512 + tid, 512 + wv * 64);
        if (tid < 64)  kst(768 + tid, 768 + wv * 64);
        // V: 128 rows x 8 granules = 1024 = 2 rounds, source pre-swizzled
#pragma unroll
        for (int r = 0; r < 2; ++r) {
            int flat = r * 512 + tid;
            int row = flat >> 3;
            int g   = (flat & 7) ^ (row & 7);
            glds16(vbase + (long)row * (B_ * S_) + k0 + g * 8,
                   Vs[buf] + (r * 512 + wv * 64) * 8);
        }
    };

    // Q fragments: 2 x 16 rows per wave
    bf16x8 qf[2][3];
#pragma unroll
    for (int g2 = 0; g2 < 2; ++g2) {
        int s = q0 + wq * 32 + g2 * 16 + l16;
        const short* qp = qk + (bS + s) * NQK_ + h * 96 + qd * 8;
        qf[g2][0] = *(const bf16x8*)(qp);
        qf[g2][1] = *(const bf16x8*)(qp + 32);
        qf[g2][2] = *(const bf16x8*)(qp + 64);
    }

    float rs[2][4] = {};          // un-reduced l accumulators (this kv half)
    f32x4 o[2][8] = {};           // partial O (this kv half)

    stage(0, 0);   // prologue

    for (int kt = 0; kt < nt; ++kt) {
        const int buf = kt & 1;
        __syncthreads();          // vmcnt(0): glds(kt) landed; buf^1 reads done
        if (kt + 1 < nt) stage((kt + 1) * 64, buf ^ 1);  // in flight

        // S = Q K^T on this wave's kv half (exp2 domain)
        f32x4 sa[2][2] = {};
#pragma unroll
        for (int j = 0; j < 2; ++j)
#pragma unroll
            for (int f = 0; f < 3; ++f) {
                bf16x8 kf = *(const bf16x8*)(Ks[buf]
                    + (we * 32 + j * 16 + l16) * 104 + f * 32 + qd * 8);
                sa[0][j] = __builtin_amdgcn_mfma_f32_16x16x32_bf16(qf[0][f], kf, sa[0][j], 0, 0, 0);
                sa[1][j] = __builtin_amdgcn_mfma_f32_16x16x32_bf16(qf[1][f], kf, sa[1][j], 0, 0, 0);
            }

        if (kt >= 2 * qt) {   // causal mask: only the two diagonal-touching tiles
#pragma unroll
            for (int g2 = 0; g2 < 2; ++g2) {
                int qg = q0 + wq * 32 + g2 * 16 + qd * 4;
#pragma unroll
                for (int j = 0; j < 2; ++j) {
                    int kg = kt * 64 + we * 32 + j * 16 + l16;
#pragma unroll
                    for (int r = 0; r < 4; ++r)
                        if (kg > qg + r) sa[g2][j][r] = -30000.0f;
                }
            }
        }

        // static-max softmax: p = exp2(s - M); store to per-wave Ps
        const int pkey = (qd & 2) << 3;   // col ^= 16 when dest row & 8
#pragma unroll
        for (int g2 = 0; g2 < 2; ++g2)
#pragma unroll
            for (int j = 0; j < 2; ++j)
#pragma unroll
                for (int r = 0; r < 4; ++r) {
                    float p = exp2f(sa[g2][j][r] - 14.5f);
                    rs[g2][r] += p;
                    Ps[wv][(g2 * 16 + qd * 4 + r) * 40 + ((j * 16 + l16) ^ pkey)] = f2bf(p);
                }

        // PV (K=32 = this wave's kv half); V-frag shared across both q halves
        bf16x8 pf[2];
#pragma unroll
        for (int g2 = 0; g2 < 2; ++g2)
            pf[g2] = *(const bf16x8*)(&Ps[wv][(g2 * 16 + l16) * 40
                        + ((qd * 8) ^ ((l16 & 8) << 1))]);
#pragma unroll
        for (int t = 0; t < 8; ++t) {
            bf16x8 vf = *(const bf16x8*)(Vs[buf] + (t * 16 + l16) * 64
                        + (((we * 4 + qd) ^ (l16 & 7)) * 8));
            o[0][t] = __builtin_amdgcn_mfma_f32_16x16x32_bf16(pf[0], vf, o[0][t], 0, 0, 0);
            o[1][t] = __builtin_amdgcn_mfma_f32_16x16x32_bf16(pf[1], vf, o[1][t], 0, 0, 0);
        }
    }

    // ---- pair reduction (we==1 -> we==0) through Ps space ----
    __syncthreads();              // all waves done with their Ps
    float* pb = (float*)&Ps[0][0];
#pragma unroll
    for (int ph = 0; ph < 4; ++ph) {     // o: 4 phases x 4 KB per pair
        int g2 = ph >> 1, th = ph & 1;
        if (we == 1) {
#pragma unroll
            for (int tt = 0; tt < 4; ++tt)
                ((f32x4*)pb)[wq * 256 + lane * 4 + tt] = o[g2][th * 4 + tt];
        }
        __syncthreads();
        if (we == 0) {
#pragma unroll
            for (int tt = 0; tt < 4; ++tt)
                o[g2][th * 4 + tt] += ((f32x4*)pb)[wq * 256 + lane * 4 + tt];
        }
        __syncthreads();
    }
    if (we == 1) {
#pragma unroll
        for (int g2 = 0; g2 < 2; ++g2) {
            f32x4 t = { rs[g2][0], rs[g2][1], rs[g2][2], rs[g2][3] };
            ((f32x4*)pb)[wq * 128 + lane * 2 + g2] = t;
        }
    }
    __syncthreads();
    if (we == 0) {
#pragma unroll
        for (int g2 = 0; g2 < 2; ++g2) {
            f32x4 t = ((f32x4*)pb)[wq * 128 + lane * 2 + g2];
            rs[g2][0] += t[0]; rs[g2][1] += t[1];
            rs[g2][2] += t[2]; rs[g2][3] += t[3];
        }

        // epilogue: reduce l once, O / l
        float inv[2][4];
#pragma unroll
        for (int g2 = 0; g2 < 2; ++g2)
#pragma unroll
            for (int r = 0; r < 4; ++r) inv[g2][r] = 1.0f / rsum16(rs[g2][r]);
#pragma unroll
        for (int g2 = 0; g2 < 2; ++g2)
#pragma unroll
            for (int t = 0; t < 8; ++t)
#pragma unroll
                for (int r = 0; r < 4; ++r) {
                    int s = q0 + wq * 32 + g2 * 16 + qd * 4 + r;
                    out[((bS + s) * H_ + h) * 128 + t * 16 + l16] =
                        f2bf(o[g2][t][r] * inv[g2][r]);
                }
    }
}

// ---------------------------------------------------------------------------
extern "C" void kernel_launch(void* const* d_in, const int* in_sizes, int n_in,
                              void* d_out, int out_size, void* d_ws, size_t ws_size,
                              hipStream_t stream)
{
    const float* hs  = (const float*)d_in[0];
    const int*   pos = (const int*)d_in[1];
    const float* Wq  = (const float*)d_in[2];
    const float* Wk  = (const float*)d_in[3];
    const float* Wv  = (const float*)d_in[4];
    const float* Wo  = (const float*)d_in[5];
    const float* qnw = (const float*)d_in[6];
    const float* knw = (const float*)d_in[7];
    float* out = (float*)d_out;
    short* ws  = (short*)d_ws;

    short* hsb   = ws;                         // 4096 x 2048
    short* Wqkvb = hsb + (long)M_ * D_;        // 2432 x 2048 (Wq|Wk|Wv rows)
    short* Wob   = Wqkvb + (long)2432 * D_;    // 2048 x 2048
    short* qk_ws = Wob + (long)D_ * 2048;      // 4096 x 1920 (q | k fused)
    short* vt_ws = qk_ws + (long)M_ * NQK_;    // 512 x 4096  (V^T)
    short* ao_ws = vt_ws + (long)512 * M_;     // 4096 x 2048

    cvt_all<<<17152, 256, 0, stream>>>(hs, Wq, Wk, Wv, Wo, ws);

    gemm_bt<3><<<dim3(M_ / 128, 2432 / 128), 256, 0, stream>>>(
        hsb, Wqkvb, qk_ws, vt_ws, M_, 2432, D_);

    rms_rope<<<(65536 + 16384) / 4, 256, 0, stream>>>(qk_ws, qnw, knw, pos);

    attn<<<dim3(32, 16), 512, 0, stream>>>(qk_ws, vt_ws, ao_ws);

    gemm_bt<2><<<dim3(M_ / 128, D_ / 128), 256, 0, stream>>>(
        ao_ws, Wob, (void*)out, nullptr, M_, D_, H_ * VD_);
}